// Round 8
// baseline (284.732 us; speedup 1.0000x reference)
//
#include <hip/hip_runtime.h>
#include <hip/hip_bf16.h>
#include <stdint.h>

#define B_ 4
#define T_ 2048
#define S_ 512
#define HID_ 2048
#define ND_ 1024
#define NH_ 16
#define HD_ 128

typedef unsigned short u16;
typedef unsigned int u32;
typedef __attribute__((ext_vector_type(8))) short bf16x8;
typedef __attribute__((ext_vector_type(4))) float f32x4;
typedef __attribute__((ext_vector_type(16))) float f32x16;
typedef __attribute__((ext_vector_type(4))) float f4;
typedef __attribute__((ext_vector_type(4))) u16 us4;
typedef __attribute__((ext_vector_type(8))) u16 us8;
typedef __attribute__((ext_vector_type(4))) u32 u32x4;

__device__ inline u16 f2bf(float f) {
  unsigned u = __builtin_bit_cast(unsigned, f);
  u += 0x7FFFu + ((u >> 16) & 1u);   // round-to-nearest-even
  return (u16)(u >> 16);
}

__device__ inline u32 cvtpk(float lo, float hi) {   // bf16(lo) | bf16(hi)<<16
  u32 r;
  asm("v_cvt_pk_bf16_f32 %0, %1, %2" : "=v"(r) : "v"(lo), "v"(hi));
  return r;
}

__device__ inline f32x4 mfma16(bf16x8 a, bf16x8 b, f32x4 c) {
  return __builtin_amdgcn_mfma_f32_16x16x32_bf16(a, b, c, 0, 0, 0);
}
__device__ inline f32x16 mfma32(bf16x8 a, bf16x8 b, f32x16 c) {
  return __builtin_amdgcn_mfma_f32_32x32x16_bf16(a, b, c, 0, 0, 0);
}

__device__ inline void gload_lds16(const u16* g, u16* l) {
  __builtin_amdgcn_global_load_lds(
      (const __attribute__((address_space(1))) unsigned int*)g,
      (__attribute__((address_space(3))) unsigned int*)l, 16, 0, 0);
}

// ---------------- fp32 -> bf16 conversion for all operands ----------------
__global__ __launch_bounds__(256) void convert_all(
    const float* __restrict__ h, const float* __restrict__ n,
    const float* __restrict__ qw, const float* __restrict__ kw,
    const float* __restrict__ vw, const float* __restrict__ ow,
    u16* __restrict__ dh, u16* __restrict__ dn, u16* __restrict__ dqw,
    u16* __restrict__ dkw, u16* __restrict__ dvw, u16* __restrict__ dow) {
  const int C0 = 4194304;            // hidden 16.78M
  const int C1 = C0 + 524288;        // notes 2.10M
  const int C2 = C1 + 1048576;       // q_w 4.19M
  const int C3 = C2 + 524288;        // k_w 2.10M
  const int C4 = C3 + 524288;        // v_w 2.10M
  const int C5 = C4 + 1048576;       // o_w 4.19M
  for (int c = blockIdx.x * blockDim.x + threadIdx.x; c < C5;
       c += gridDim.x * blockDim.x) {
    const float* s; u16* d; int o;
    if (c < C0)      { s = h;  d = dh;  o = c; }
    else if (c < C1) { s = n;  d = dn;  o = c - C0; }
    else if (c < C2) { s = qw; d = dqw; o = c - C1; }
    else if (c < C3) { s = kw; d = dkw; o = c - C2; }
    else if (c < C4) { s = vw; d = dvw; o = c - C3; }
    else             { s = ow; d = dow; o = c - C4; }
    f4 v = ((const f4*)s)[o];
    us4 r = { f2bf(v[0]), f2bf(v[1]), f2bf(v[2]), f2bf(v[3]) };
    ((us4*)d)[o] = r;
  }
}

// ---------------- small GEMM (128^2 tile, m97 structure) ----------------
template <bool OUT_BF16>
__global__ __launch_bounds__(256) void gemm_bt(
    const u16* __restrict__ A, const u16* __restrict__ Bm,
    const float* __restrict__ bias, void* __restrict__ Cout,
    int M, int N, int K) {
  __shared__ u16 As[128 * 32];
  __shared__ u16 Bs[128 * 32];
  const int tid = threadIdx.x;
  const int lane = tid & 63;
  const int wave = tid >> 6;
  const int wr = (wave >> 1) * 64;
  const int wc = (wave & 1) * 64;
  const int c15 = lane & 15;
  const int g = lane >> 4;
  const int bx = blockIdx.x, by = blockIdx.y;

  const u16* gA = A + (size_t)(by * 128 + (tid >> 2)) * K + (tid & 3) * 8;
  const u16* gB = Bm + (size_t)(bx * 128 + (tid >> 2)) * K + (tid & 3) * 8;

  f32x4 acc[4][4];
#pragma unroll
  for (int i = 0; i < 4; ++i)
#pragma unroll
    for (int j = 0; j < 4; ++j) acc[i][j] = (f32x4){0.f, 0.f, 0.f, 0.f};

  for (int k0 = 0; k0 < K; k0 += 32) {
    gload_lds16(gA + k0, &As[wave * 512]);
    gload_lds16(gA + (size_t)64 * K + k0, &As[2048 + wave * 512]);
    gload_lds16(gB + k0, &Bs[wave * 512]);
    gload_lds16(gB + (size_t)64 * K + k0, &Bs[2048 + wave * 512]);
    __syncthreads();
    bf16x8 af[4], bfr[4];
#pragma unroll
    for (int mt = 0; mt < 4; ++mt)
      af[mt] = *(const bf16x8*)&As[(wr + mt * 16 + c15) * 32 + g * 8];
#pragma unroll
    for (int nt = 0; nt < 4; ++nt)
      bfr[nt] = *(const bf16x8*)&Bs[(wc + nt * 16 + c15) * 32 + g * 8];
#pragma unroll
    for (int mt = 0; mt < 4; ++mt)
#pragma unroll
      for (int nt = 0; nt < 4; ++nt)
        acc[mt][nt] = mfma16(af[mt], bfr[nt], acc[mt][nt]);
    __syncthreads();
  }

#pragma unroll
  for (int mt = 0; mt < 4; ++mt)
#pragma unroll
    for (int nt = 0; nt < 4; ++nt) {
      const int m = by * 128 + wr + mt * 16 + g * 4;
      const int n = bx * 128 + wc + nt * 16 + c15;
      const float bv = bias[n];
#pragma unroll
      for (int r = 0; r < 4; ++r) {
        const float v = acc[mt][nt][r] + bv;
        if (OUT_BF16)
          ((u16*)Cout)[(size_t)(m + r) * N + n] = f2bf(v);
        else
          ((float*)Cout)[(size_t)(m + r) * N + n] = v;
      }
    }
}

// ------ big GEMM: m201-style 8-phase template, 256^2 tile, BK=64 -----------
// 8 waves (2M x 4N), wave tile 128x64. LDS = 2 K-tile buffers x 64KB
// (A-lo/A-hi/B-lo/B-hi halves of 16KB = 128 rows x 64 u16 cols).
// Per K-tile j, 4 phases of {ds_read quadrant; stage 1 half; BAR; lgkm(0);
// setprio(1); 16 MFMA; setprio(0); BAR}:
//  P1: read A0(8)+B0(4), stage A-hi(j+1)   -> MFMA Q0 = A0xB0 (K=64)
//  P2: read B1(4),       stage B-lo(j+1)   -> MFMA Q1 = A0xB1
//  P3: read A1(8),       stage B-hi(j+1) + A-lo(j+2)  -> MFMA Q3 = A1xB1
//      (A-lo(j+2) writes the LIVE buffer: its region's reads completed at
//       P1's lgkm(0)+BAR, two barriers earlier; sched_barrier(0) pins issue)
//  P4: no reads,                            -> MFMA Q2 = A1xB0 (B0 held)
//      then boundary: vmcnt(2) retires exactly tile j+1's 4 halves
//      (in-order queue: [Alo(j+1),Ahi(j+1),Blo(j+1),Bhi(j+1),Alo(j+2)]);
//      vmcnt(0) only at the tail. One barrier.
// st_16x32 swizzle: u16 col ^= 16 when row bit2 set; pre-swizzled global
// source + swizzled ds_read (both-sides involution, G21).
template <bool OUT_BF16>
__global__ __launch_bounds__(512, 2) void gemm8p(
    const u16* __restrict__ A, const u16* __restrict__ Bm,
    const float* __restrict__ bias, void* __restrict__ Cout,
    int M, int N, int K) {
  extern __shared__ u16 lds[];          // 2 x 32768 u16 = 128 KB
  const int tid = threadIdx.x;
  const int lane = tid & 63, wave = tid >> 6;
  const int wm = wave >> 2, wn = wave & 3;
  const int c15 = lane & 15, g = lane >> 4;
  const int bid = blockIdx.y * gridDim.x + blockIdx.x;
  const int sw = (bid & 7) * 32 + (bid >> 3);   // XCD-contiguous, bijective
  const int bn = sw & 7, bm = sw >> 3;
  const int NT = K >> 6;                        // BK = 64

  // staging source (pre-swizzled): load i in {0,1}: row (i*8+w)*8 + (l>>3),
  // byte col ((l&7)*16) ^ ((l>>5)<<5)  [row bit2 == lane bit5]
  const int r0 = wave * 8 + (lane >> 3);
  const int scol = ((lane & 7) * 16) ^ ((lane >> 5) << 5);
  const size_t dK = (size_t)64 * K;             // +64 rows (load i=1)
  const u16* pAlo = A + (size_t)(bm * 256 + r0) * K + (scol >> 1);
  const u16* pAhi = A + (size_t)(bm * 256 + 128 + r0) * K + (scol >> 1);
  const u16* pBlo = Bm + (size_t)(bn * 256 + r0) * K + (scol >> 1);
  const u16* pBhi = Bm + (size_t)(bn * 256 + 128 + r0) * K + (scol >> 1);

#define STG(p, dst)                                  \
  do {                                               \
    gload_lds16((p), (dst) + wave * 512);            \
    gload_lds16((p) + dK, (dst) + 4096 + wave * 512);\
    (p) += 64;                                       \
  } while (0)

  // ds_read offsets (u16): swizzled k-col base; frag (f,h) at +f*1024+h*32
  const int sg = (g * 8) ^ ((c15 & 4) << 2);
  const int aoff = wm * 8192 + c15 * 64 + sg;
  const int boff = 16384 + (wn >> 1) * 8192 + (wn & 1) * 4096 + c15 * 64 + sg;

  f32x4 acc[8][4];
#pragma unroll
  for (int i = 0; i < 8; ++i)
#pragma unroll
    for (int j = 0; j < 4; ++j) acc[i][j] = (f32x4){0.f, 0.f, 0.f, 0.f};

  // prologue: tile0's 4 halves -> buf0, A-lo(1) -> buf1; retire tile0
  STG(pAlo, lds);
  STG(pAhi, lds + 8192);
  STG(pBlo, lds + 16384);
  STG(pBhi, lds + 24576);
  STG(pAlo, lds + 32768);
  asm volatile("s_waitcnt vmcnt(2)" ::: "memory");
  __builtin_amdgcn_s_barrier();

  for (int j = 0; j < NT; ++j) {
    const int cu = (j & 1) << 15;
    const u16* cb = lds + cu;              // read buffer (tile j)
    u16* nb = lds + (cu ^ 32768);          // stage buffer (tile j+1)
    const bool s1 = (j + 1 < NT);
    const bool s2 = (j + 2 < NT);

    // ---------------- P1: A0 + B0; stage A-hi(j+1); MFMA Q0
    bf16x8 aL[4][2], bL[2][2];
#pragma unroll
    for (int fm = 0; fm < 4; ++fm)
#pragma unroll
      for (int h = 0; h < 2; ++h)
        aL[fm][h] = *(const bf16x8*)(cb + aoff + fm * 1024 + h * 32);
#pragma unroll
    for (int fn = 0; fn < 2; ++fn)
#pragma unroll
      for (int h = 0; h < 2; ++h)
        bL[fn][h] = *(const bf16x8*)(cb + boff + fn * 1024 + h * 32);
    if (s1) STG(pAhi, nb + 8192);
    __builtin_amdgcn_s_barrier();
    asm volatile("s_waitcnt lgkmcnt(0)" ::: "memory");
    __builtin_amdgcn_s_setprio(1);
#pragma unroll
    for (int fm = 0; fm < 4; ++fm)
#pragma unroll
      for (int fn = 0; fn < 2; ++fn) {
        acc[fm][fn] = mfma16(aL[fm][0], bL[fn][0], acc[fm][fn]);
        acc[fm][fn] = mfma16(aL[fm][1], bL[fn][1], acc[fm][fn]);
      }
    __builtin_amdgcn_s_setprio(0);
    __builtin_amdgcn_s_barrier();

    // ---------------- P2: B1; stage B-lo(j+1); MFMA Q1
    bf16x8 bH[2][2];
#pragma unroll
    for (int fn = 0; fn < 2; ++fn)
#pragma unroll
      for (int h = 0; h < 2; ++h)
        bH[fn][h] = *(const bf16x8*)(cb + boff + (2 + fn) * 1024 + h * 32);
    if (s1) STG(pBlo, nb + 16384);
    __builtin_amdgcn_s_barrier();
    asm volatile("s_waitcnt lgkmcnt(0)" ::: "memory");
    __builtin_amdgcn_s_setprio(1);
#pragma unroll
    for (int fm = 0; fm < 4; ++fm)
#pragma unroll
      for (int fn = 0; fn < 2; ++fn) {
        acc[fm][2 + fn] = mfma16(aL[fm][0], bH[fn][0], acc[fm][2 + fn]);
        acc[fm][2 + fn] = mfma16(aL[fm][1], bH[fn][1], acc[fm][2 + fn]);
      }
    __builtin_amdgcn_s_setprio(0);
    __builtin_amdgcn_s_barrier();

    // ---------------- P3: A1; stage B-hi(j+1) then A-lo(j+2); MFMA Q3
    bf16x8 aH[4][2];
#pragma unroll
    for (int fm = 0; fm < 4; ++fm)
#pragma unroll
      for (int h = 0; h < 2; ++h)
        aH[fm][h] = *(const bf16x8*)(cb + aoff + (4 + fm) * 1024 + h * 32);
    if (s1) STG(pBhi, nb + 24576);
    __builtin_amdgcn_sched_barrier(0);   // pin: live-buf stage stays here
    if (s2) STG(pAlo, lds + cu);         // live buffer; A reads done at P1
    __builtin_amdgcn_s_barrier();
    asm volatile("s_waitcnt lgkmcnt(0)" ::: "memory");
    __builtin_amdgcn_s_setprio(1);
#pragma unroll
    for (int fm = 0; fm < 4; ++fm)
#pragma unroll
      for (int fn = 0; fn < 2; ++fn) {
        acc[4 + fm][2 + fn] = mfma16(aH[fm][0], bH[fn][0], acc[4 + fm][2 + fn]);
        acc[4 + fm][2 + fn] = mfma16(aH[fm][1], bH[fn][1], acc[4 + fm][2 + fn]);
      }
    __builtin_amdgcn_s_setprio(0);
    __builtin_amdgcn_s_barrier();

    // ---------------- P4: MFMA Q2 (A1 x B0, both held); boundary wait
    __builtin_amdgcn_s_setprio(1);
#pragma unroll
    for (int fm = 0; fm < 4; ++fm)
#pragma unroll
      for (int fn = 0; fn < 2; ++fn) {
        acc[4 + fm][fn] = mfma16(aH[fm][0], bL[fn][0], acc[4 + fm][fn]);
        acc[4 + fm][fn] = mfma16(aH[fm][1], bL[fn][1], acc[4 + fm][fn]);
      }
    __builtin_amdgcn_s_setprio(0);
    if (s2) asm volatile("s_waitcnt vmcnt(2)" ::: "memory");
    else    asm volatile("s_waitcnt vmcnt(0)" ::: "memory");
    __builtin_amdgcn_s_barrier();
  }
#undef STG

  // epilogue: bias + store (C row = g*4+r, col = c15 per fragment)
#pragma unroll
  for (int mf = 0; mf < 8; ++mf)
#pragma unroll
    for (int nf = 0; nf < 4; ++nf) {
      const int m = bm * 256 + wm * 128 + mf * 16 + g * 4;
      const int n = bn * 256 + wn * 64 + nf * 16 + c15;
      const float bv = bias[n];
#pragma unroll
      for (int r = 0; r < 4; ++r) {
        const float v = acc[mf][nf][r] + bv;
        if (OUT_BF16)
          ((u16*)Cout)[(size_t)(m + r) * N + n] = f2bf(v);
        else
          ((float*)Cout)[(size_t)(m + r) * N + n] = v;
      }
    }
}

// ---------------- V transpose: (B,S,H,D) -> (B,H,D,S) ----------------
__global__ __launch_bounds__(256) void transpose_v(const u16* __restrict__ v,
                                                   u16* __restrict__ vt) {
  __shared__ u16 tile[32][36];
  const int s0 = blockIdx.x * 32;
  const int bh = blockIdx.y;
  const int d0 = blockIdx.z * 32;
  const int b = bh >> 4, h = bh & 15;
  const int tid = threadIdx.x;
  const int sl = tid >> 3, dl = (tid & 7) * 4;
  us4 val = *(const us4*)(v + (size_t)(b * S_ + s0 + sl) * HID_ + h * HD_ + d0 + dl);
  *(us4*)&tile[sl][dl] = val;
  __syncthreads();
  const int dl2 = tid >> 3, sl2 = (tid & 7) * 4;
  us4 outv = { tile[sl2 + 0][dl2], tile[sl2 + 1][dl2],
               tile[sl2 + 2][dl2], tile[sl2 + 3][dl2] };
  *(us4*)(vt + ((size_t)bh * HD_ + d0 + dl2) * S_ + s0 + sl2) = outv;
}

// ---------------- fused masked cross-attention, 32x32 MFMA ----------------
__global__ __launch_bounds__(256) void attn_fwd(
    const u16* __restrict__ q, const u16* __restrict__ k,
    const u16* __restrict__ vt, const int* __restrict__ mask,
    const float* __restrict__ gate, u16* __restrict__ ctx) {
  __shared__ u16 smem[17408];   // [0,8192) K bufs x2; [8192,16384) V bufs x2;
                                // epilogue reuses [0,17408) as 4x stride-136
  __shared__ float addend[S_];
  const int tid = threadIdx.x, lane = tid & 63, wave = tid >> 6;
  const int bh = blockIdx.y, b = bh >> 4, h = bh & 15;
  const int tw = blockIdx.x * 128 + wave * 32;
  const int l31 = lane & 31, hi = lane >> 5;

  const u16* kb  = k + (size_t)b * S_ * HID_ + h * HD_;
  const u16* vtb = vt + (size_t)bh * HD_ * S_;

  const u16* sp[4];
  int dj[4];
  u16* ldsbase;
  ptrdiff_t stride;
  if (wave < 2) {
    ldsbase = smem;                       // K: 32 s-rows x 256B
    stride = 32 * HID_;
#pragma unroll
    for (int i = 0; i < 4; ++i) {
      const int jj = wave * 4 + i;
      const int row = jj * 4 + (lane >> 4);
      const int cb = (lane & 15) * 16;
      const int cbp = cb ^ ((row & 7) << 4);
      sp[i] = kb + (size_t)row * HID_ + (cbp >> 1);
      dj[i] = jj * 512;
    }
  } else {
    ldsbase = smem + 8192;                // V^T: 128 d-rows x 64B
    stride = 32;
#pragma unroll
    for (int i = 0; i < 4; ++i) {
      const int jj = (wave - 2) * 4 + i;
      const int d = jj * 16 + (lane >> 2);
      const int cb = (lane & 3) * 16;
      const int cbp = cb ^ ((d & 3) << 4);
      sp[i] = vtb + (size_t)d * S_ + (cbp >> 1);
      dj[i] = jj * 512;
    }
  }
#define STAGE(cur)                                            \
  do {                                                        \
    _Pragma("unroll") for (int i_ = 0; i_ < 4; ++i_) {        \
      gload_lds16(sp[i_], ldsbase + (cur) * 4096 + dj[i_]);   \
      sp[i_] += stride;                                       \
    }                                                         \
  } while (0)

  STAGE(0);

  for (int s = tid; s < S_; s += 256)
    addend[s] = mask[b * S_ + s] ? 0.f : -1e30f;

  const u16* qrow = q + (size_t)(b * T_ + tw + l31) * HID_ + h * HD_;
  bf16x8 qf[8];
#pragma unroll
  for (int dc = 0; dc < 8; ++dc)
    qf[dc] = *(const bf16x8*)&qrow[dc * 16 + hi * 8];

  int kofs[8];
#pragma unroll
  for (int dc = 0; dc < 8; ++dc)
    kofs[dc] = l31 * 128 + (((dc * 32 + hi * 16) ^ ((l31 & 7) << 4)) >> 1);
  const int vcol0 = ((hi * 16) ^ ((l31 & 3) << 4)) >> 1;
  const int vcol1 = ((32 + hi * 16) ^ ((l31 & 3) << 4)) >> 1;

  float m_run = -1e30f, l_run = 0.f;
  f32x16 ct[4];
#pragma unroll
  for (int i = 0; i < 4; ++i)
#pragma unroll
    for (int r = 0; r < 16; ++r) ct[i][r] = 0.f;
  const float scale = 0.08838834764831845f;  // 1/sqrt(128)

  __syncthreads();   // buf0 staged, addend ready

  for (int it = 0; it < 16; ++it) {
    const int cur = it & 1;
    if (it < 15) STAGE(cur ^ 1);
    const int s0 = it * 32;
    const u16* kt = smem + cur * 4096;
    const u16* vl = smem + 8192 + cur * 4096;

    f32x16 st;
#pragma unroll
    for (int r = 0; r < 16; ++r) st[r] = 0.f;
    __builtin_amdgcn_s_setprio(1);
#pragma unroll
    for (int dc = 0; dc < 8; ++dc) {
      bf16x8 kf = *(const bf16x8*)&kt[kofs[dc]];
      st = mfma32(kf, qf[dc], st);
    }
    __builtin_amdgcn_s_setprio(0);

    float sc[16];
#pragma unroll
    for (int rq = 0; rq < 4; ++rq) {
      f4 ad = *(const f4*)&addend[s0 + rq * 8 + hi * 4];
#pragma unroll
      for (int m = 0; m < 4; ++m)
        sc[rq * 4 + m] = st[rq * 4 + m] * scale + ad[m];
    }
    float tm = sc[0];
#pragma unroll
    for (int i = 1; i < 16; ++i) tm = fmaxf(tm, sc[i]);
    tm = fmaxf(tm, __shfl_xor(tm, 32));
    const float nm = fmaxf(m_run, tm);
    if (!__all(nm - m_run <= 8.f)) {
      const float corr = __expf(m_run - nm);
      l_run *= corr;
#pragma unroll
      for (int db = 0; db < 4; ++db)
#pragma unroll
        for (int r = 0; r < 16; ++r) ct[db][r] *= corr;
      m_run = nm;
    }
    float p[16], ps = 0.f;
#pragma unroll
    for (int i = 0; i < 16; ++i) { p[i] = __expf(sc[i] - m_run); ps += p[i]; }
    ps += __shfl_xor(ps, 32);
    l_run += ps;

    u32 w[8], x[8];
#pragma unroll
    for (int q2 = 0; q2 < 4; ++q2) {
      w[2 * q2]     = cvtpk(p[4 * q2],     p[4 * q2 + 1]);
      w[2 * q2 + 1] = cvtpk(p[4 * q2 + 2], p[4 * q2 + 3]);
    }
#pragma unroll
    for (int i = 0; i < 8; ++i) x[i] = __shfl_xor((int)w[i], 32);
    const u32x4 f0 = hi ? (u32x4){x[2], x[3], w[2], w[3]}
                        : (u32x4){w[0], w[1], x[0], x[1]};
    const u32x4 f1 = hi ? (u32x4){x[6], x[7], w[6], w[7]}
                        : (u32x4){w[4], w[5], x[4], x[5]};
    const bf16x8 pf0 = __builtin_bit_cast(bf16x8, f0);
    const bf16x8 pf1 = __builtin_bit_cast(bf16x8, f1);

    __builtin_amdgcn_s_setprio(1);
#pragma unroll
    for (int db = 0; db < 4; ++db) {
      bf16x8 vf0 = *(const bf16x8*)&vl[db * 1024 + l31 * 32 + vcol0];
      ct[db] = mfma32(vf0, pf0, ct[db]);
      bf16x8 vf1 = *(const bf16x8*)&vl[db * 1024 + l31 * 32 + vcol1];
      ct[db] = mfma32(vf1, pf1, ct[db]);
    }
    __builtin_amdgcn_s_setprio(0);

    __syncthreads();
  }
#undef STAGE

  const float gsig = 1.f / (1.f + __expf(-gate[0]));
  const float inv = gsig / l_run;
  u16* c_lds = smem + wave * 4352;    // 32 rows x 136 u16
#pragma unroll
  for (int db = 0; db < 4; ++db)
#pragma unroll
    for (int rq = 0; rq < 4; ++rq) {
      us4 o = { f2bf(ct[db][rq * 4 + 0] * inv), f2bf(ct[db][rq * 4 + 1] * inv),
                f2bf(ct[db][rq * 4 + 2] * inv), f2bf(ct[db][rq * 4 + 3] * inv) };
      *(us4*)&c_lds[l31 * 136 + db * 32 + rq * 8 + hi * 4] = o;
    }
  u16* crow = ctx + (size_t)(b * T_ + tw) * HID_ + h * HD_;
#pragma unroll
  for (int rep = 0; rep < 8; ++rep) {
    const int tt = (lane >> 4) + rep * 4;
    us8 valv = *(const us8*)&c_lds[tt * 136 + (lane & 15) * 8];
    *(us8*)&crow[(size_t)tt * HID_ + (lane & 15) * 8] = valv;
  }
}

// ---------------- launch ----------------
extern "C" void kernel_launch(void* const* d_in, const int* in_sizes, int n_in,
                              void* d_out, int out_size, void* d_ws, size_t ws_size,
                              hipStream_t stream) {
  (void)in_sizes; (void)n_in; (void)out_size; (void)ws_size;
  const float* hs   = (const float*)d_in[0];
  const float* nts  = (const float*)d_in[1];
  const int*   mask = (const int*)d_in[2];
  const float* qw   = (const float*)d_in[3];
  const float* qb   = (const float*)d_in[4];
  const float* kw   = (const float*)d_in[5];
  const float* kbi  = (const float*)d_in[6];
  const float* vw   = (const float*)d_in[7];
  const float* vbi  = (const float*)d_in[8];
  const float* ow   = (const float*)d_in[9];
  const float* obi  = (const float*)d_in[10];
  const float* gate = (const float*)d_in[11];
  float* out = (float*)d_out;

  char* w = (char*)d_ws;
  u16* h_bf   = (u16*)(w + 0);          // 33,554,432 B
  u16* n_bf   = (u16*)(w + 33554432);   //  4,194,304 B
  u16* qw_bf  = (u16*)(w + 37748736);   //  8,388,608 B
  u16* kw_bf  = (u16*)(w + 46137344);   //  4,194,304 B
  u16* vw_bf  = (u16*)(w + 50331648);   //  4,194,304 B
  u16* ow_bf  = (u16*)(w + 54525952);   //  8,388,608 B
  u16* q_bf   = (u16*)(w + 62914560);   // 33,554,432 B
  u16* k_bf   = (u16*)(w + 96468992);   //  8,388,608 B
  u16* v_bf   = (u16*)(w + 104857600);  //  8,388,608 B
  u16* vt_bf  = (u16*)(w + 113246208);  //  8,388,608 B  (end 121,634,816)
  u16* ctx_bf = h_bf;                   // alias: hidden_bf16 dead after Q-proj

  hipFuncSetAttribute(reinterpret_cast<const void*>(&gemm8p<true>),
                      hipFuncAttributeMaxDynamicSharedMemorySize, 131072);
  hipFuncSetAttribute(reinterpret_cast<const void*>(&gemm8p<false>),
                      hipFuncAttributeMaxDynamicSharedMemorySize, 131072);

  convert_all<<<dim3(2048), dim3(256), 0, stream>>>(
      hs, nts, qw, kw, vw, ow, h_bf, n_bf, qw_bf, kw_bf, vw_bf, ow_bf);
  gemm_bt<true><<<dim3(16, 16), dim3(256), 0, stream>>>(
      n_bf, kw_bf, kbi, k_bf, 2048, 2048, 1024);
  gemm_bt<true><<<dim3(16, 16), dim3(256), 0, stream>>>(
      n_bf, vw_bf, vbi, v_bf, 2048, 2048, 1024);
  transpose_v<<<dim3(16, 64, 4), dim3(256), 0, stream>>>(v_bf, vt_bf);
  // Q projection: M=8192, N=2048, K=2048 — grid 8x32 = 256 blocks (1/CU)
  gemm8p<true><<<dim3(8, 32), dim3(512), 131072, stream>>>(
      h_bf, qw_bf, qb, q_bf, 8192, 2048, 2048);
  attn_fwd<<<dim3(16, 64), dim3(256), 0, stream>>>(
      q_bf, k_bf, vt_bf, mask, gate, ctx_bf);
  // Output projection -> fp32 d_out
  gemm8p<false><<<dim3(8, 32), dim3(512), 131072, stream>>>(
      ctx_bf, ow_bf, obi, out, 8192, 2048, 2048);
}

// Round 9
// 284.339 us; speedup vs baseline: 1.0014x; 1.0014x over previous
//
#include <hip/hip_runtime.h>
#include <hip/hip_bf16.h>
#include <stdint.h>

#define B_ 4
#define T_ 2048
#define S_ 512
#define HID_ 2048
#define ND_ 1024
#define NH_ 16
#define HD_ 128

typedef unsigned short u16;
typedef unsigned int u32;
typedef __attribute__((ext_vector_type(8))) short bf16x8;
typedef __attribute__((ext_vector_type(4))) float f32x4;
typedef __attribute__((ext_vector_type(16))) float f32x16;
typedef __attribute__((ext_vector_type(4))) float f4;
typedef __attribute__((ext_vector_type(4))) u16 us4;
typedef __attribute__((ext_vector_type(8))) u16 us8;
typedef __attribute__((ext_vector_type(4))) u32 u32x4;

__device__ inline u16 f2bf(float f) {
  unsigned u = __builtin_bit_cast(unsigned, f);
  u += 0x7FFFu + ((u >> 16) & 1u);   // round-to-nearest-even
  return (u16)(u >> 16);
}

__device__ inline u32 cvtpk(float lo, float hi) {   // bf16(lo) | bf16(hi)<<16
  u32 r;
  asm("v_cvt_pk_bf16_f32 %0, %1, %2" : "=v"(r) : "v"(lo), "v"(hi));
  return r;
}

__device__ inline f32x4 mfma16(bf16x8 a, bf16x8 b, f32x4 c) {
  return __builtin_amdgcn_mfma_f32_16x16x32_bf16(a, b, c, 0, 0, 0);
}
__device__ inline f32x16 mfma32(bf16x8 a, bf16x8 b, f32x16 c) {
  return __builtin_amdgcn_mfma_f32_32x32x16_bf16(a, b, c, 0, 0, 0);
}

__device__ inline void gload_lds16(const u16* g, u16* l) {
  __builtin_amdgcn_global_load_lds(
      (const __attribute__((address_space(1))) unsigned int*)g,
      (__attribute__((address_space(3))) unsigned int*)l, 16, 0, 0);
}

// ---------------- fp32 -> bf16 conversion for all operands ----------------
__global__ __launch_bounds__(256) void convert_all(
    const float* __restrict__ h, const float* __restrict__ n,
    const float* __restrict__ qw, const float* __restrict__ kw,
    const float* __restrict__ vw, const float* __restrict__ ow,
    u16* __restrict__ dh, u16* __restrict__ dn, u16* __restrict__ dqw,
    u16* __restrict__ dkw, u16* __restrict__ dvw, u16* __restrict__ dow) {
  const int C0 = 4194304;            // hidden 16.78M
  const int C1 = C0 + 524288;        // notes 2.10M
  const int C2 = C1 + 1048576;       // q_w 4.19M
  const int C3 = C2 + 524288;        // k_w 2.10M
  const int C4 = C3 + 524288;        // v_w 2.10M
  const int C5 = C4 + 1048576;       // o_w 4.19M
  for (int c = blockIdx.x * blockDim.x + threadIdx.x; c < C5;
       c += gridDim.x * blockDim.x) {
    const float* s; u16* d; int o;
    if (c < C0)      { s = h;  d = dh;  o = c; }
    else if (c < C1) { s = n;  d = dn;  o = c - C0; }
    else if (c < C2) { s = qw; d = dqw; o = c - C1; }
    else if (c < C3) { s = kw; d = dkw; o = c - C2; }
    else if (c < C4) { s = vw; d = dvw; o = c - C3; }
    else             { s = ow; d = dow; o = c - C4; }
    f4 v = ((const f4*)s)[o];
    us4 r = { f2bf(v[0]), f2bf(v[1]), f2bf(v[2]), f2bf(v[3]) };
    ((us4*)d)[o] = r;
  }
}

// ---------------- small GEMM (128^2 tile, m97 structure) ----------------
template <bool OUT_BF16>
__global__ __launch_bounds__(256) void gemm_bt(
    const u16* __restrict__ A, const u16* __restrict__ Bm,
    const float* __restrict__ bias, void* __restrict__ Cout,
    int M, int N, int K) {
  __shared__ u16 As[128 * 32];
  __shared__ u16 Bs[128 * 32];
  const int tid = threadIdx.x;
  const int lane = tid & 63;
  const int wave = tid >> 6;
  const int wr = (wave >> 1) * 64;
  const int wc = (wave & 1) * 64;
  const int c15 = lane & 15;
  const int g = lane >> 4;
  const int bx = blockIdx.x, by = blockIdx.y;

  const u16* gA = A + (size_t)(by * 128 + (tid >> 2)) * K + (tid & 3) * 8;
  const u16* gB = Bm + (size_t)(bx * 128 + (tid >> 2)) * K + (tid & 3) * 8;

  f32x4 acc[4][4];
#pragma unroll
  for (int i = 0; i < 4; ++i)
#pragma unroll
    for (int j = 0; j < 4; ++j) acc[i][j] = (f32x4){0.f, 0.f, 0.f, 0.f};

  for (int k0 = 0; k0 < K; k0 += 32) {
    gload_lds16(gA + k0, &As[wave * 512]);
    gload_lds16(gA + (size_t)64 * K + k0, &As[2048 + wave * 512]);
    gload_lds16(gB + k0, &Bs[wave * 512]);
    gload_lds16(gB + (size_t)64 * K + k0, &Bs[2048 + wave * 512]);
    __syncthreads();
    bf16x8 af[4], bfr[4];
#pragma unroll
    for (int mt = 0; mt < 4; ++mt)
      af[mt] = *(const bf16x8*)&As[(wr + mt * 16 + c15) * 32 + g * 8];
#pragma unroll
    for (int nt = 0; nt < 4; ++nt)
      bfr[nt] = *(const bf16x8*)&Bs[(wc + nt * 16 + c15) * 32 + g * 8];
#pragma unroll
    for (int mt = 0; mt < 4; ++mt)
#pragma unroll
      for (int nt = 0; nt < 4; ++nt)
        acc[mt][nt] = mfma16(af[mt], bfr[nt], acc[mt][nt]);
    __syncthreads();
  }

#pragma unroll
  for (int mt = 0; mt < 4; ++mt)
#pragma unroll
    for (int nt = 0; nt < 4; ++nt) {
      const int m = by * 128 + wr + mt * 16 + g * 4;
      const int n = bx * 128 + wc + nt * 16 + c15;
      const float bv = bias[n];
#pragma unroll
      for (int r = 0; r < 4; ++r) {
        const float v = acc[mt][nt][r] + bv;
        if (OUT_BF16)
          ((u16*)Cout)[(size_t)(m + r) * N + n] = f2bf(v);
        else
          ((float*)Cout)[(size_t)(m + r) * N + n] = v;
      }
    }
}

// ------ big GEMM: 8-phase template, 256^2 tile, BK=64, DEEP prefetch -------
// 8 waves (2M x 4N), wave tile 128x64. LDS = 2 K-tile buffers x 64KB
// (A-lo/A-hi/B-lo/B-hi halves, each 128 rows x 64 u16). Tile j's data lives
// in buf[j&1], staged during tile j-2 (region-death-ordered into the then-
// live buffer):
//  P1: read A0(8)+B0(4)               -> BAR; lgkm0; 16 MFMA Q0; BAR
//  P2: read B1(4)                     -> BAR; lgkm0; Q1; BAR
//      (after P2's trailing BAR, ALL waves' B-region reads are drained:
//       each wave's lgkm(0) precedes its barrier arrival)
//  P3: read A1(8); stage B-lo/B-hi(j+2) into LIVE buffer B regions (dead)
//                                     -> BAR; lgkm0; Q3; BAR
//      (after P3's trailing BAR, A regions are dead)
//  P4: stage A-lo/A-hi(j+2) into LIVE A regions (dead); Q2 (regs held);
//      boundary: vmcnt(8) retires exactly tile j+1's 8 loads (issued a FULL
//      tile earlier -> no stall); vmcnt(0) only at tail; BAR.
// st_16x32 swizzle on both pre-swizzled global source and ds_read (G21).
template <bool OUT_BF16>
__global__ __launch_bounds__(512, 2) void gemm8p(
    const u16* __restrict__ A, const u16* __restrict__ Bm,
    const float* __restrict__ bias, void* __restrict__ Cout,
    int M, int N, int K) {
  extern __shared__ u16 lds[];          // 2 x 32768 u16 = 128 KB
  const int tid = threadIdx.x;
  const int lane = tid & 63, wave = tid >> 6;
  const int wm = wave >> 2, wn = wave & 3;
  const int c15 = lane & 15, g = lane >> 4;
  const int bid = blockIdx.y * gridDim.x + blockIdx.x;
  const int sw = (bid & 7) * 32 + (bid >> 3);   // XCD-contiguous, bijective
  const int bn = sw & 7, bm = sw >> 3;
  const int NT = K >> 6;                        // BK = 64

  // staging source (pre-swizzled): row = wave*8 + (l>>3),
  // byte col ((l&7)*16) ^ ((l>>5)<<5)  [row bit2 == lane bit5]
  const int r0 = wave * 8 + (lane >> 3);
  const int scol = ((lane & 7) * 16) ^ ((lane >> 5) << 5);
  const size_t dK = (size_t)64 * K;             // +64 rows (2nd sweep)
  const u16* pAlo = A + (size_t)(bm * 256 + r0) * K + (scol >> 1);
  const u16* pAhi = A + (size_t)(bm * 256 + 128 + r0) * K + (scol >> 1);
  const u16* pBlo = Bm + (size_t)(bn * 256 + r0) * K + (scol >> 1);
  const u16* pBhi = Bm + (size_t)(bn * 256 + 128 + r0) * K + (scol >> 1);

#define STG(p, dst)                                  \
  do {                                               \
    gload_lds16((p), (dst) + wave * 512);            \
    gload_lds16((p) + dK, (dst) + 4096 + wave * 512);\
    (p) += 64;                                       \
  } while (0)

  // ds_read offsets (u16): swizzled k-col base; frag (f,h) at +f*1024+h*32
  const int sg = (g * 8) ^ ((c15 & 4) << 2);
  const int aoff = wm * 8192 + c15 * 64 + sg;
  const int boff = 16384 + (wn >> 1) * 8192 + (wn & 1) * 4096 + c15 * 64 + sg;

  f32x4 acc[8][4];
#pragma unroll
  for (int i = 0; i < 8; ++i)
#pragma unroll
    for (int j = 0; j < 4; ++j) acc[i][j] = (f32x4){0.f, 0.f, 0.f, 0.f};

  // prologue: tile0 -> buf0, tile1 -> buf1 (16 loads); retire tile0
  STG(pAlo, lds);
  STG(pAhi, lds + 8192);
  STG(pBlo, lds + 16384);
  STG(pBhi, lds + 24576);
  STG(pAlo, lds + 32768);
  STG(pAhi, lds + 40960);
  STG(pBlo, lds + 49152);
  STG(pBhi, lds + 57344);
  asm volatile("s_waitcnt vmcnt(8)" ::: "memory");
  __builtin_amdgcn_s_barrier();

  for (int j = 0; j < NT; ++j) {
    const int cu = (j & 1) << 15;
    const u16* cb = lds + cu;              // read buffer (tile j)
    u16* rb = lds + cu;                    // stage target = LIVE buffer
    const bool s2 = (j + 2 < NT);

    // ---------------- P1: read A0 + B0; MFMA Q0
    bf16x8 aL[4][2], bL[2][2];
#pragma unroll
    for (int fm = 0; fm < 4; ++fm)
#pragma unroll
      for (int h = 0; h < 2; ++h)
        aL[fm][h] = *(const bf16x8*)(cb + aoff + fm * 1024 + h * 32);
#pragma unroll
    for (int fn = 0; fn < 2; ++fn)
#pragma unroll
      for (int h = 0; h < 2; ++h)
        bL[fn][h] = *(const bf16x8*)(cb + boff + fn * 1024 + h * 32);
    __builtin_amdgcn_s_barrier();
    asm volatile("s_waitcnt lgkmcnt(0)" ::: "memory");
    __builtin_amdgcn_sched_barrier(0);
    __builtin_amdgcn_s_setprio(1);
#pragma unroll
    for (int fm = 0; fm < 4; ++fm)
#pragma unroll
      for (int fn = 0; fn < 2; ++fn) {
        acc[fm][fn] = mfma16(aL[fm][0], bL[fn][0], acc[fm][fn]);
        acc[fm][fn] = mfma16(aL[fm][1], bL[fn][1], acc[fm][fn]);
      }
    __builtin_amdgcn_s_setprio(0);
    __builtin_amdgcn_s_barrier();

    // ---------------- P2: read B1; MFMA Q1
    bf16x8 bH[2][2];
#pragma unroll
    for (int fn = 0; fn < 2; ++fn)
#pragma unroll
      for (int h = 0; h < 2; ++h)
        bH[fn][h] = *(const bf16x8*)(cb + boff + (2 + fn) * 1024 + h * 32);
    __builtin_amdgcn_s_barrier();
    asm volatile("s_waitcnt lgkmcnt(0)" ::: "memory");
    __builtin_amdgcn_sched_barrier(0);
    __builtin_amdgcn_s_setprio(1);
#pragma unroll
    for (int fm = 0; fm < 4; ++fm)
#pragma unroll
      for (int fn = 0; fn < 2; ++fn) {
        acc[fm][2 + fn] = mfma16(aL[fm][0], bH[fn][0], acc[fm][2 + fn]);
        acc[fm][2 + fn] = mfma16(aL[fm][1], bH[fn][1], acc[fm][2 + fn]);
      }
    __builtin_amdgcn_s_setprio(0);
    __builtin_amdgcn_s_barrier();
    // B regions of the live buffer are now dead (all waves drained reads
    // at their lgkm(0) before arriving at the barrier above).

    // ---------------- P3: read A1; stage B(j+2) into live B regions; Q3
    bf16x8 aH[4][2];
#pragma unroll
    for (int fm = 0; fm < 4; ++fm)
#pragma unroll
      for (int h = 0; h < 2; ++h)
        aH[fm][h] = *(const bf16x8*)(cb + aoff + (4 + fm) * 1024 + h * 32);
    if (s2) {
      STG(pBlo, rb + 16384);
      STG(pBhi, rb + 24576);
    }
    __builtin_amdgcn_s_barrier();
    asm volatile("s_waitcnt lgkmcnt(0)" ::: "memory");
    __builtin_amdgcn_sched_barrier(0);
    __builtin_amdgcn_s_setprio(1);
#pragma unroll
    for (int fm = 0; fm < 4; ++fm)
#pragma unroll
      for (int fn = 0; fn < 2; ++fn) {
        acc[4 + fm][2 + fn] = mfma16(aH[fm][0], bH[fn][0], acc[4 + fm][2 + fn]);
        acc[4 + fm][2 + fn] = mfma16(aH[fm][1], bH[fn][1], acc[4 + fm][2 + fn]);
      }
    __builtin_amdgcn_s_setprio(0);
    __builtin_amdgcn_s_barrier();
    // A regions now dead.

    // ---------------- P4: stage A(j+2) into live A regions; MFMA Q2
    if (s2) {
      STG(pAlo, rb);
      STG(pAhi, rb + 8192);
    }
    __builtin_amdgcn_s_setprio(1);
#pragma unroll
    for (int fm = 0; fm < 4; ++fm)
#pragma unroll
      for (int fn = 0; fn < 2; ++fn) {
        acc[4 + fm][fn] = mfma16(aH[fm][0], bL[fn][0], acc[4 + fm][fn]);
        acc[4 + fm][fn] = mfma16(aH[fm][1], bL[fn][1], acc[4 + fm][fn]);
      }
    __builtin_amdgcn_s_setprio(0);
    if (j + 1 < NT) {
      // need tile j+1 landed (staged during tile j-1; >= 1 full tile ago)
      if (s2) asm volatile("s_waitcnt vmcnt(8)" ::: "memory");
      else    asm volatile("s_waitcnt vmcnt(0)" ::: "memory");
      __builtin_amdgcn_s_barrier();
    }
  }
#undef STG

  // epilogue: bias + store (C row = g*4+r, col = c15 per fragment)
#pragma unroll
  for (int mf = 0; mf < 8; ++mf)
#pragma unroll
    for (int nf = 0; nf < 4; ++nf) {
      const int m = bm * 256 + wm * 128 + mf * 16 + g * 4;
      const int n = bn * 256 + wn * 64 + nf * 16 + c15;
      const float bv = bias[n];
#pragma unroll
      for (int r = 0; r < 4; ++r) {
        const float v = acc[mf][nf][r] + bv;
        if (OUT_BF16)
          ((u16*)Cout)[(size_t)(m + r) * N + n] = f2bf(v);
        else
          ((float*)Cout)[(size_t)(m + r) * N + n] = v;
      }
    }
}

// ---------------- V transpose: (B,S,H,D) -> (B,H,D,S) ----------------
__global__ __launch_bounds__(256) void transpose_v(const u16* __restrict__ v,
                                                   u16* __restrict__ vt) {
  __shared__ u16 tile[32][36];
  const int s0 = blockIdx.x * 32;
  const int bh = blockIdx.y;
  const int d0 = blockIdx.z * 32;
  const int b = bh >> 4, h = bh & 15;
  const int tid = threadIdx.x;
  const int sl = tid >> 3, dl = (tid & 7) * 4;
  us4 val = *(const us4*)(v + (size_t)(b * S_ + s0 + sl) * HID_ + h * HD_ + d0 + dl);
  *(us4*)&tile[sl][dl] = val;
  __syncthreads();
  const int dl2 = tid >> 3, sl2 = (tid & 7) * 4;
  us4 outv = { tile[sl2 + 0][dl2], tile[sl2 + 1][dl2],
               tile[sl2 + 2][dl2], tile[sl2 + 3][dl2] };
  *(us4*)(vt + ((size_t)bh * HD_ + d0 + dl2) * S_ + s0 + sl2) = outv;
}

// ---------------- fused masked cross-attention, 32x32 MFMA ----------------
__global__ __launch_bounds__(256) void attn_fwd(
    const u16* __restrict__ q, const u16* __restrict__ k,
    const u16* __restrict__ vt, const int* __restrict__ mask,
    const float* __restrict__ gate, u16* __restrict__ ctx) {
  __shared__ u16 smem[17408];   // [0,8192) K bufs x2; [8192,16384) V bufs x2;
                                // epilogue reuses [0,17408) as 4x stride-136
  __shared__ float addend[S_];
  const int tid = threadIdx.x, lane = tid & 63, wave = tid >> 6;
  const int bh = blockIdx.y, b = bh >> 4, h = bh & 15;
  const int tw = blockIdx.x * 128 + wave * 32;
  const int l31 = lane & 31, hi = lane >> 5;

  const u16* kb  = k + (size_t)b * S_ * HID_ + h * HD_;
  const u16* vtb = vt + (size_t)bh * HD_ * S_;

  const u16* sp[4];
  int dj[4];
  u16* ldsbase;
  ptrdiff_t stride;
  if (wave < 2) {
    ldsbase = smem;                       // K: 32 s-rows x 256B
    stride = 32 * HID_;
#pragma unroll
    for (int i = 0; i < 4; ++i) {
      const int jj = wave * 4 + i;
      const int row = jj * 4 + (lane >> 4);
      const int cb = (lane & 15) * 16;
      const int cbp = cb ^ ((row & 7) << 4);
      sp[i] = kb + (size_t)row * HID_ + (cbp >> 1);
      dj[i] = jj * 512;
    }
  } else {
    ldsbase = smem + 8192;                // V^T: 128 d-rows x 64B
    stride = 32;
#pragma unroll
    for (int i = 0; i < 4; ++i) {
      const int jj = (wave - 2) * 4 + i;
      const int d = jj * 16 + (lane >> 2);
      const int cb = (lane & 3) * 16;
      const int cbp = cb ^ ((d & 3) << 4);
      sp[i] = vtb + (size_t)d * S_ + (cbp >> 1);
      dj[i] = jj * 512;
    }
  }
#define STAGE(cur)                                            \
  do {                                                        \
    _Pragma("unroll") for (int i_ = 0; i_ < 4; ++i_) {        \
      gload_lds16(sp[i_], ldsbase + (cur) * 4096 + dj[i_]);   \
      sp[i_] += stride;                                       \
    }                                                         \
  } while (0)

  STAGE(0);

  for (int s = tid; s < S_; s += 256)
    addend[s] = mask[b * S_ + s] ? 0.f : -1e30f;

  const u16* qrow = q + (size_t)(b * T_ + tw + l31) * HID_ + h * HD_;
  bf16x8 qf[8];
#pragma unroll
  for (int dc = 0; dc < 8; ++dc)
    qf[dc] = *(const bf16x8*)&qrow[dc * 16 + hi * 8];

  int kofs[8];
#pragma unroll
  for (int dc = 0; dc < 8; ++dc)
    kofs[dc] = l31 * 128 + (((dc * 32 + hi * 16) ^ ((l31 & 7) << 4)) >> 1);
  const int vcol0 = ((hi * 16) ^ ((l31 & 3) << 4)) >> 1;
  const int vcol1 = ((32 + hi * 16) ^ ((l31 & 3) << 4)) >> 1;

  float m_run = -1e30f, l_run = 0.f;
  f32x16 ct[4];
#pragma unroll
  for (int i = 0; i < 4; ++i)
#pragma unroll
    for (int r = 0; r < 16; ++r) ct[i][r] = 0.f;
  const float scale = 0.08838834764831845f;  // 1/sqrt(128)

  __syncthreads();   // buf0 staged, addend ready

  for (int it = 0; it < 16; ++it) {
    const int cur = it & 1;
    if (it < 15) STAGE(cur ^ 1);
    const int s0 = it * 32;
    const u16* kt = smem + cur * 4096;
    const u16* vl = smem + 8192 + cur * 4096;

    f32x16 st;
#pragma unroll
    for (int r = 0; r < 16; ++r) st[r] = 0.f;
    __builtin_amdgcn_s_setprio(1);
#pragma unroll
    for (int dc = 0; dc < 8; ++dc) {
      bf16x8 kf = *(const bf16x8*)&kt[kofs[dc]];
      st = mfma32(kf, qf[dc], st);
    }
    __builtin_amdgcn_s_setprio(0);

    float sc[16];
#pragma unroll
    for (int rq = 0; rq < 4; ++rq) {
      f4 ad = *(const f4*)&addend[s0 + rq * 8 + hi * 4];
#pragma unroll
      for (int m = 0; m < 4; ++m)
        sc[rq * 4 + m] = st[rq * 4 + m] * scale + ad[m];
    }
    float tm = sc[0];
#pragma unroll
    for (int i = 1; i < 16; ++i) tm = fmaxf(tm, sc[i]);
    tm = fmaxf(tm, __shfl_xor(tm, 32));
    const float nm = fmaxf(m_run, tm);
    if (!__all(nm - m_run <= 8.f)) {
      const float corr = __expf(m_run - nm);
      l_run *= corr;
#pragma unroll
      for (int db = 0; db < 4; ++db)
#pragma unroll
        for (int r = 0; r < 16; ++r) ct[db][r] *= corr;
      m_run = nm;
    }
    float p[16], ps = 0.f;
#pragma unroll
    for (int i = 0; i < 16; ++i) { p[i] = __expf(sc[i] - m_run); ps += p[i]; }
    ps += __shfl_xor(ps, 32);
    l_run += ps;

    u32 w[8], x[8];
#pragma unroll
    for (int q2 = 0; q2 < 4; ++q2) {
      w[2 * q2]     = cvtpk(p[4 * q2],     p[4 * q2 + 1]);
      w[2 * q2 + 1] = cvtpk(p[4 * q2 + 2], p[4 * q2 + 3]);
    }
#pragma unroll
    for (int i = 0; i < 8; ++i) x[i] = __shfl_xor((int)w[i], 32);
    const u32x4 f0 = hi ? (u32x4){x[2], x[3], w[2], w[3]}
                        : (u32x4){w[0], w[1], x[0], x[1]};
    const u32x4 f1 = hi ? (u32x4){x[6], x[7], w[6], w[7]}
                        : (u32x4){w[4], w[5], x[4], x[5]};
    const bf16x8 pf0 = __builtin_bit_cast(bf16x8, f0);
    const bf16x8 pf1 = __builtin_bit_cast(bf16x8, f1);

    __builtin_amdgcn_s_setprio(1);
#pragma unroll
    for (int db = 0; db < 4; ++db) {
      bf16x8 vf0 = *(const bf16x8*)&vl[db * 1024 + l31 * 32 + vcol0];
      ct[db] = mfma32(vf0, pf0, ct[db]);
      bf16x8 vf1 = *(const bf16x8*)&vl[db * 1024 + l31 * 32 + vcol1];
      ct[db] = mfma32(vf1, pf1, ct[db]);
    }
    __builtin_amdgcn_s_setprio(0);

    __syncthreads();
  }
#undef STAGE

  const float gsig = 1.f / (1.f + __expf(-gate[0]));
  const float inv = gsig / l_run;
  u16* c_lds = smem + wave * 4352;    // 32 rows x 136 u16
#pragma unroll
  for (int db = 0; db < 4; ++db)
#pragma unroll
    for (int rq = 0; rq < 4; ++rq) {
      us4 o = { f2bf(ct[db][rq * 4 + 0] * inv), f2bf(ct[db][rq * 4 + 1] * inv),
                f2bf(ct[db][rq * 4 + 2] * inv), f2bf(ct[db][rq * 4 + 3] * inv) };
      *(us4*)&c_lds[l31 * 136 + db * 32 + rq * 8 + hi * 4] = o;
    }
  u16* crow = ctx + (size_t)(b * T_ + tw) * HID_ + h * HD_;
#pragma unroll
  for (int rep = 0; rep < 8; ++rep) {
    const int tt = (lane >> 4) + rep * 4;
    us8 valv = *(const us8*)&c_lds[tt * 136 + (lane & 15) * 8];
    *(us8*)&crow[(size_t)tt * HID_ + (lane & 15) * 8] = valv;
  }
}

// ---------------- launch ----------------
extern "C" void kernel_launch(void* const* d_in, const int* in_sizes, int n_in,
                              void* d_out, int out_size, void* d_ws, size_t ws_size,
                              hipStream_t stream) {
  (void)in_sizes; (void)n_in; (void)out_size; (void)ws_size;
  const float* hs   = (const float*)d_in[0];
  const float* nts  = (const float*)d_in[1];
  const int*   mask = (const int*)d_in[2];
  const float* qw   = (const float*)d_in[3];
  const float* qb   = (const float*)d_in[4];
  const float* kw   = (const float*)d_in[5];
  const float* kbi  = (const float*)d_in[6];
  const float* vw   = (const float*)d_in[7];
  const float* vbi  = (const float*)d_in[8];
  const float* ow   = (const float*)d_in[9];
  const float* obi  = (const float*)d_in[10];
  const float* gate = (const float*)d_in[11];
  float* out = (float*)d_out;

  char* w = (char*)d_ws;
  u16* h_bf   = (u16*)(w + 0);          // 33,554,432 B
  u16* n_bf   = (u16*)(w + 33554432);   //  4,194,304 B
  u16* qw_bf  = (u16*)(w + 37748736);   //  8,388,608 B
  u16* kw_bf  = (u16*)(w + 46137344);   //  4,194,304 B
  u16* vw_bf  = (u16*)(w + 50331648);   //  4,194,304 B
  u16* ow_bf  = (u16*)(w + 54525952);   //  8,388,608 B
  u16* q_bf   = (u16*)(w + 62914560);   // 33,554,432 B
  u16* k_bf   = (u16*)(w + 96468992);   //  8,388,608 B
  u16* v_bf   = (u16*)(w + 104857600);  //  8,388,608 B
  u16* vt_bf  = (u16*)(w + 113246208);  //  8,388,608 B  (end 121,634,816)
  u16* ctx_bf = h_bf;                   // alias: hidden_bf16 dead after Q-proj

  hipFuncSetAttribute(reinterpret_cast<const void*>(&gemm8p<true>),
                      hipFuncAttributeMaxDynamicSharedMemorySize, 131072);
  hipFuncSetAttribute(reinterpret_cast<const void*>(&gemm8p<false>),
                      hipFuncAttributeMaxDynamicSharedMemorySize, 131072);

  convert_all<<<dim3(2048), dim3(256), 0, stream>>>(
      hs, nts, qw, kw, vw, ow, h_bf, n_bf, qw_bf, kw_bf, vw_bf, ow_bf);
  gemm_bt<true><<<dim3(16, 16), dim3(256), 0, stream>>>(
      n_bf, kw_bf, kbi, k_bf, 2048, 2048, 1024);
  gemm_bt<true><<<dim3(16, 16), dim3(256), 0, stream>>>(
      n_bf, vw_bf, vbi, v_bf, 2048, 2048, 1024);
  transpose_v<<<dim3(16, 64, 4), dim3(256), 0, stream>>>(v_bf, vt_bf);
  // Q projection: M=8192, N=2048, K=2048 — grid 8x32 = 256 blocks (1/CU)
  gemm8p<true><<<dim3(8, 32), dim3(512), 131072, stream>>>(
      h_bf, qw_bf, qb, q_bf, 8192, 2048, 2048);
  attn_fwd<<<dim3(16, 64), dim3(256), 0, stream>>>(
      q_bf, k_bf, vt_bf, mask, gate, ctx_bf);
  // Output projection -> fp32 d_out
  gemm8p<false><<<dim3(8, 32), dim3(512), 131072, stream>>>(
      ctx_bf, ow_bf, obi, out, 8192, 2048, 2048);
}

// Round 11
// 279.524 us; speedup vs baseline: 1.0186x; 1.0172x over previous
//
#include <hip/hip_runtime.h>
#include <hip/hip_bf16.h>
#include <stdint.h>

#define B_ 4
#define T_ 2048
#define S_ 512
#define HID_ 2048
#define ND_ 1024
#define NH_ 16
#define HD_ 128

typedef unsigned short u16;
typedef unsigned int u32;
typedef __attribute__((ext_vector_type(8))) short bf16x8;
typedef __attribute__((ext_vector_type(4))) float f32x4;
typedef __attribute__((ext_vector_type(16))) float f32x16;
typedef __attribute__((ext_vector_type(4))) float f4;
typedef __attribute__((ext_vector_type(4))) u16 us4;
typedef __attribute__((ext_vector_type(8))) u16 us8;
typedef __attribute__((ext_vector_type(4))) u32 u32x4;

__device__ inline u16 f2bf(float f) {
  unsigned u = __builtin_bit_cast(unsigned, f);
  u += 0x7FFFu + ((u >> 16) & 1u);   // round-to-nearest-even
  return (u16)(u >> 16);
}

__device__ inline u32 cvtpk(float lo, float hi) {   // bf16(lo) | bf16(hi)<<16
  u32 r;
  asm("v_cvt_pk_bf16_f32 %0, %1, %2" : "=v"(r) : "v"(lo), "v"(hi));
  return r;
}

__device__ inline f32x4 mfma16(bf16x8 a, bf16x8 b, f32x4 c) {
  return __builtin_amdgcn_mfma_f32_16x16x32_bf16(a, b, c, 0, 0, 0);
}
__device__ inline f32x16 mfma32(bf16x8 a, bf16x8 b, f32x16 c) {
  return __builtin_amdgcn_mfma_f32_32x32x16_bf16(a, b, c, 0, 0, 0);
}

__device__ inline void gload_lds16(const u16* g, u16* l) {
  __builtin_amdgcn_global_load_lds(
      (const __attribute__((address_space(1))) unsigned int*)g,
      (__attribute__((address_space(3))) unsigned int*)l, 16, 0, 0);
}

// fenced barrier: s_barrier that is ALSO a compiler memory fence, so memory
// ops (ds_read / global_load_lds) cannot be hoisted or sunk across it.
// Raw __builtin_amdgcn_s_barrier() is NOT an IR memory fence — hipcc may
// hoist next-tile ds_reads above it (R10 post-timing race).
#define FENCED_BARRIER() asm volatile("s_barrier" ::: "memory")

// ---------------- fp32 -> bf16 conversion for all operands ----------------
__global__ __launch_bounds__(256) void convert_all(
    const float* __restrict__ h, const float* __restrict__ n,
    const float* __restrict__ qw, const float* __restrict__ kw,
    const float* __restrict__ vw, const float* __restrict__ ow,
    u16* __restrict__ dh, u16* __restrict__ dn, u16* __restrict__ dqw,
    u16* __restrict__ dkw, u16* __restrict__ dvw, u16* __restrict__ dow) {
  const int C0 = 4194304;            // hidden 16.78M
  const int C1 = C0 + 524288;        // notes 2.10M
  const int C2 = C1 + 1048576;       // q_w 4.19M
  const int C3 = C2 + 524288;        // k_w 2.10M
  const int C4 = C3 + 524288;        // v_w 2.10M
  const int C5 = C4 + 1048576;       // o_w 4.19M
  for (int c = blockIdx.x * blockDim.x + threadIdx.x; c < C5;
       c += gridDim.x * blockDim.x) {
    const float* s; u16* d; int o;
    if (c < C0)      { s = h;  d = dh;  o = c; }
    else if (c < C1) { s = n;  d = dn;  o = c - C0; }
    else if (c < C2) { s = qw; d = dqw; o = c - C1; }
    else if (c < C3) { s = kw; d = dkw; o = c - C2; }
    else if (c < C4) { s = vw; d = dvw; o = c - C3; }
    else             { s = ow; d = dow; o = c - C4; }
    f4 v = ((const f4*)s)[o];
    us4 r = { f2bf(v[0]), f2bf(v[1]), f2bf(v[2]), f2bf(v[3]) };
    ((us4*)d)[o] = r;
  }
}

// ---------------- small GEMM (128^2 tile, m97 structure) ----------------
template <bool OUT_BF16>
__global__ __launch_bounds__(256) void gemm_bt(
    const u16* __restrict__ A, const u16* __restrict__ Bm,
    const float* __restrict__ bias, void* __restrict__ Cout,
    int M, int N, int K) {
  __shared__ u16 As[128 * 32];
  __shared__ u16 Bs[128 * 32];
  const int tid = threadIdx.x;
  const int lane = tid & 63;
  const int wave = tid >> 6;
  const int wr = (wave >> 1) * 64;
  const int wc = (wave & 1) * 64;
  const int c15 = lane & 15;
  const int g = lane >> 4;
  const int bx = blockIdx.x, by = blockIdx.y;

  const u16* gA = A + (size_t)(by * 128 + (tid >> 2)) * K + (tid & 3) * 8;
  const u16* gB = Bm + (size_t)(bx * 128 + (tid >> 2)) * K + (tid & 3) * 8;

  f32x4 acc[4][4];
#pragma unroll
  for (int i = 0; i < 4; ++i)
#pragma unroll
    for (int j = 0; j < 4; ++j) acc[i][j] = (f32x4){0.f, 0.f, 0.f, 0.f};

  for (int k0 = 0; k0 < K; k0 += 32) {
    gload_lds16(gA + k0, &As[wave * 512]);
    gload_lds16(gA + (size_t)64 * K + k0, &As[2048 + wave * 512]);
    gload_lds16(gB + k0, &Bs[wave * 512]);
    gload_lds16(gB + (size_t)64 * K + k0, &Bs[2048 + wave * 512]);
    __syncthreads();
    bf16x8 af[4], bfr[4];
#pragma unroll
    for (int mt = 0; mt < 4; ++mt)
      af[mt] = *(const bf16x8*)&As[(wr + mt * 16 + c15) * 32 + g * 8];
#pragma unroll
    for (int nt = 0; nt < 4; ++nt)
      bfr[nt] = *(const bf16x8*)&Bs[(wc + nt * 16 + c15) * 32 + g * 8];
#pragma unroll
    for (int mt = 0; mt < 4; ++mt)
#pragma unroll
      for (int nt = 0; nt < 4; ++nt)
        acc[mt][nt] = mfma16(af[mt], bfr[nt], acc[mt][nt]);
    __syncthreads();
  }

#pragma unroll
  for (int mt = 0; mt < 4; ++mt)
#pragma unroll
    for (int nt = 0; nt < 4; ++nt) {
      const int m = by * 128 + wr + mt * 16 + g * 4;
      const int n = bx * 128 + wc + nt * 16 + c15;
      const float bv = bias[n];
#pragma unroll
      for (int r = 0; r < 4; ++r) {
        const float v = acc[mt][nt][r] + bv;
        if (OUT_BF16)
          ((u16*)Cout)[(size_t)(m + r) * N + n] = f2bf(v);
        else
          ((float*)Cout)[(size_t)(m + r) * N + n] = v;
      }
    }
}

// ---- big GEMM: 256^2 tile, 4-buffer, ONE fenced barrier + counted vmcnt ---
// R6 structure (best measured: 69.4 us, MfmaUtil 40.4%, conflicts 0) with the
// barrier replaced by FENCED_BARRIER() so the compiler cannot hoist the next
// tile's ds_reads above the rendezvous (R10's post-timing race).
template <bool OUT_BF16>
__global__ __launch_bounds__(512, 2) void gemm_pipe(
    const u16* __restrict__ A, const u16* __restrict__ Bm,
    const float* __restrict__ bias, void* __restrict__ Cout,
    int M, int N, int K) {
  extern __shared__ u16 lds[];          // 4 bufs x (A 8192 + B 8192) u16
  const int tid = threadIdx.x;
  const int lane = tid & 63, wave = tid >> 6;
  const int wm = wave >> 2, wn = wave & 3;
  const int c15 = lane & 15, g = lane >> 4;
  const int bid = blockIdx.y * gridDim.x + blockIdx.x;
  const int sw = (bid & 7) * 32 + (bid >> 3);   // XCD-contiguous, bijective
  const int bn = sw & 7, bm = sw >> 3;
  const int NT = K >> 5;

  const int srow = tid >> 2;
  const int sx = (tid & 3) ^ ((srow >> 1) & 3);
  const u16* pa0 = A + (size_t)(bm * 256 + srow) * K + sx * 8;
  const u16* pa1 = A + (size_t)(bm * 256 + 128 + srow) * K + sx * 8;
  const u16* pb0 = Bm + (size_t)(bn * 256 + srow) * K + sx * 8;
  const u16* pb1 = Bm + (size_t)(bn * 256 + 128 + srow) * K + sx * 8;

  const int xr = (c15 >> 1) & 3;
  const int aoff = wm * 4096 + c15 * 32 + (g ^ xr) * 8;
  const int boff = 8192 + wn * 2048 + c15 * 32 + (g ^ xr) * 8;

  f32x4 acc[8][4];
#pragma unroll
  for (int i = 0; i < 8; ++i)
#pragma unroll
    for (int j = 0; j < 4; ++j) acc[i][j] = (f32x4){0.f, 0.f, 0.f, 0.f};

  // prologue: tile0 -> buf0, tile1 -> buf1; wait tile0 (retire oldest 4)
  {
    u16* sA = lds + wave * 512;
    u16* sB = lds + 8192 + wave * 512;
    gload_lds16(pa0, sA);          gload_lds16(pa1, sA + 4096);
    gload_lds16(pb0, sB);          gload_lds16(pb1, sB + 4096);
    pa0 += 32; pa1 += 32; pb0 += 32; pb1 += 32;
    gload_lds16(pa0, sA + 16384);  gload_lds16(pa1, sA + 20480);
    gload_lds16(pb0, sB + 16384);  gload_lds16(pb1, sB + 20480);
    pa0 += 32; pa1 += 32; pb0 += 32; pb1 += 32;
  }
  asm volatile("s_waitcnt vmcnt(4)" ::: "memory");
  FENCED_BARRIER();

  for (int t = 0; t < NT; ++t) {
    const bool more = (t + 2 < NT);
    const u16* cb = lds + (t & 3) * 16384;
    u16* sb = lds + ((t + 2) & 3) * 16384;

    bf16x8 a[8], b[4];
#pragma unroll
    for (int mf = 0; mf < 4; ++mf)
      a[mf] = *(const bf16x8*)(cb + aoff + mf * 512);
#pragma unroll
    for (int nf = 0; nf < 4; ++nf)
      b[nf] = *(const bf16x8*)(cb + boff + nf * 512);
#pragma unroll
    for (int mf = 4; mf < 8; ++mf)
      a[mf] = *(const bf16x8*)(cb + aoff + mf * 512);

    if (more) {
      gload_lds16(pa0, sb + wave * 512);
      gload_lds16(pa1, sb + 4096 + wave * 512);
      gload_lds16(pb0, sb + 8192 + wave * 512);
      gload_lds16(pb1, sb + 12288 + wave * 512);
      pa0 += 32; pa1 += 32; pb0 += 32; pb1 += 32;
    }

    __builtin_amdgcn_s_setprio(1);
#pragma unroll
    for (int mf = 0; mf < 8; ++mf)
#pragma unroll
      for (int nf = 0; nf < 4; ++nf)
        acc[mf][nf] = mfma16(a[mf], b[nf], acc[mf][nf]);
    __builtin_amdgcn_s_setprio(0);

    if (more) asm volatile("s_waitcnt vmcnt(4)" ::: "memory");
    else      asm volatile("s_waitcnt vmcnt(0)" ::: "memory");
    FENCED_BARRIER();
  }

  // epilogue: bias + store (C row = g*4+r, col = c15 per fragment)
#pragma unroll
  for (int mf = 0; mf < 8; ++mf)
#pragma unroll
    for (int nf = 0; nf < 4; ++nf) {
      const int m = bm * 256 + wm * 128 + mf * 16 + g * 4;
      const int n = bn * 256 + wn * 64 + nf * 16 + c15;
      const float bv = bias[n];
#pragma unroll
      for (int r = 0; r < 4; ++r) {
        const float v = acc[mf][nf][r] + bv;
        if (OUT_BF16)
          ((u16*)Cout)[(size_t)(m + r) * N + n] = f2bf(v);
        else
          ((float*)Cout)[(size_t)(m + r) * N + n] = v;
      }
    }
}

// ---------------- V transpose: (B,S,H,D) -> (B,H,D,S) ----------------
__global__ __launch_bounds__(256) void transpose_v(const u16* __restrict__ v,
                                                   u16* __restrict__ vt) {
  __shared__ u16 tile[32][36];
  const int s0 = blockIdx.x * 32;
  const int bh = blockIdx.y;
  const int d0 = blockIdx.z * 32;
  const int b = bh >> 4, h = bh & 15;
  const int tid = threadIdx.x;
  const int sl = tid >> 3, dl = (tid & 7) * 4;
  us4 val = *(const us4*)(v + (size_t)(b * S_ + s0 + sl) * HID_ + h * HD_ + d0 + dl);
  *(us4*)&tile[sl][dl] = val;
  __syncthreads();
  const int dl2 = tid >> 3, sl2 = (tid & 7) * 4;
  us4 outv = { tile[sl2 + 0][dl2], tile[sl2 + 1][dl2],
               tile[sl2 + 2][dl2], tile[sl2 + 3][dl2] };
  *(us4*)(vt + ((size_t)bh * HD_ + d0 + dl2) * S_ + s0 + sl2) = outv;
}

// ---------------- fused masked cross-attention, 32x32 MFMA ----------------
// (R10 version: decorrelated V swizzle ((d>>1)&3) on both staging source and
// read offset, QK accumulator split. Synchronization is full __syncthreads()
// everywhere — sound by construction.)
__global__ __launch_bounds__(256) void attn_fwd(
    const u16* __restrict__ q, const u16* __restrict__ k,
    const u16* __restrict__ vt, const int* __restrict__ mask,
    const float* __restrict__ gate, u16* __restrict__ ctx) {
  __shared__ u16 smem[17408];   // [0,8192) K bufs x2; [8192,16384) V bufs x2;
                                // epilogue reuses [0,17408) as 4x stride-136
  __shared__ float addend[S_];
  const int tid = threadIdx.x, lane = tid & 63, wave = tid >> 6;
  const int bh = blockIdx.y, b = bh >> 4, h = bh & 15;
  const int tw = blockIdx.x * 128 + wave * 32;
  const int l31 = lane & 31, hi = lane >> 5;

  const u16* kb  = k + (size_t)b * S_ * HID_ + h * HD_;
  const u16* vtb = vt + (size_t)bh * HD_ * S_;

  const u16* sp[4];
  int dj[4];
  u16* ldsbase;
  ptrdiff_t stride;
  if (wave < 2) {
    ldsbase = smem;                       // K: 32 s-rows x 256B
    stride = 32 * HID_;
#pragma unroll
    for (int i = 0; i < 4; ++i) {
      const int jj = wave * 4 + i;
      const int row = jj * 4 + (lane >> 4);
      const int cb = (lane & 15) * 16;
      const int cbp = cb ^ ((row & 7) << 4);
      sp[i] = kb + (size_t)row * HID_ + (cbp >> 1);
      dj[i] = jj * 512;
    }
  } else {
    ldsbase = smem + 8192;                // V^T: 128 d-rows x 64B
    stride = 32;
#pragma unroll
    for (int i = 0; i < 4; ++i) {
      const int jj = (wave - 2) * 4 + i;
      const int d = jj * 16 + (lane >> 2);
      const int cb = (lane & 3) * 16;
      const int cbp = cb ^ (((d >> 1) & 3) << 4);   // decorrelated swizzle
      sp[i] = vtb + (size_t)d * S_ + (cbp >> 1);
      dj[i] = jj * 512;
    }
  }
#define STAGE(cur)                                            \
  do {                                                        \
    _Pragma("unroll") for (int i_ = 0; i_ < 4; ++i_) {        \
      gload_lds16(sp[i_], ldsbase + (cur) * 4096 + dj[i_]);   \
      sp[i_] += stride;                                       \
    }                                                         \
  } while (0)

  STAGE(0);

  for (int s = tid; s < S_; s += 256)
    addend[s] = mask[b * S_ + s] ? 0.f : -1e30f;

  const u16* qrow = q + (size_t)(b * T_ + tw + l31) * HID_ + h * HD_;
  bf16x8 qf[8];
#pragma unroll
  for (int dc = 0; dc < 8; ++dc)
    qf[dc] = *(const bf16x8*)&qrow[dc * 16 + hi * 8];

  int kofs[8];
#pragma unroll
  for (int dc = 0; dc < 8; ++dc)
    kofs[dc] = l31 * 128 + (((dc * 32 + hi * 16) ^ ((l31 & 7) << 4)) >> 1);
  const int vswz = ((l31 >> 1) & 3) << 4;               // matches staging
  const int vcol0 = ((hi * 16) ^ vswz) >> 1;
  const int vcol1 = ((32 + hi * 16) ^ vswz) >> 1;

  float m_run = -1e30f, l_run = 0.f;
  f32x16 ct[4];
#pragma unroll
  for (int i = 0; i < 4; ++i)
#pragma unroll
    for (int r = 0; r < 16; ++r) ct[i][r] = 0.f;
  const float scale = 0.08838834764831845f;  // 1/sqrt(128)

  __syncthreads();   // buf0 staged, addend ready

  for (int it = 0; it < 16; ++it) {
    const int cur = it & 1;
    if (it < 15) STAGE(cur ^ 1);
    const int s0 = it * 32;
    const u16* kt = smem + cur * 4096;
    const u16* vl = smem + 8192 + cur * 4096;

    // QK^T with split accumulators (halve the serial MFMA chain)
    f32x16 st_a, st_b;
#pragma unroll
    for (int r = 0; r < 16; ++r) { st_a[r] = 0.f; st_b[r] = 0.f; }
    __builtin_amdgcn_s_setprio(1);
#pragma unroll
    for (int dc = 0; dc < 4; ++dc) {
      bf16x8 kf0 = *(const bf16x8*)&kt[kofs[dc]];
      bf16x8 kf1 = *(const bf16x8*)&kt[kofs[4 + dc]];
      st_a = mfma32(kf0, qf[dc], st_a);
      st_b = mfma32(kf1, qf[4 + dc], st_b);
    }
    __builtin_amdgcn_s_setprio(0);

    float sc[16];
#pragma unroll
    for (int rq = 0; rq < 4; ++rq) {
      f4 ad = *(const f4*)&addend[s0 + rq * 8 + hi * 4];
#pragma unroll
      for (int m = 0; m < 4; ++m)
        sc[rq * 4 + m] = (st_a[rq * 4 + m] + st_b[rq * 4 + m]) * scale + ad[m];
    }
    float tm = sc[0];
#pragma unroll
    for (int i = 1; i < 16; ++i) tm = fmaxf(tm, sc[i]);
    tm = fmaxf(tm, __shfl_xor(tm, 32));
    const float nm = fmaxf(m_run, tm);
    if (!__all(nm - m_run <= 8.f)) {
      const float corr = __expf(m_run - nm);
      l_run *= corr;
#pragma unroll
      for (int db = 0; db < 4; ++db)
#pragma unroll
        for (int r = 0; r < 16; ++r) ct[db][r] *= corr;
      m_run = nm;
    }
    float p[16], ps = 0.f;
#pragma unroll
    for (int i = 0; i < 16; ++i) { p[i] = __expf(sc[i] - m_run); ps += p[i]; }
    ps += __shfl_xor(ps, 32);
    l_run += ps;

    u32 w[8], x[8];
#pragma unroll
    for (int q2 = 0; q2 < 4; ++q2) {
      w[2 * q2]     = cvtpk(p[4 * q2],     p[4 * q2 + 1]);
      w[2 * q2 + 1] = cvtpk(p[4 * q2 + 2], p[4 * q2 + 3]);
    }
#pragma unroll
    for (int i = 0; i < 8; ++i) x[i] = __shfl_xor((int)w[i], 32);
    const u32x4 f0 = hi ? (u32x4){x[2], x[3], w[2], w[3]}
                        : (u32x4){w[0], w[1], x[0], x[1]};
    const u32x4 f1 = hi ? (u32x4){x[6], x[7], w[6], w[7]}
                        : (u32x4){w[4], w[5], x[4], x[5]};
    const bf16x8 pf0 = __builtin_bit_cast(bf16x8, f0);
    const bf16x8 pf1 = __builtin_bit_cast(bf16x8, f1);

    __builtin_amdgcn_s_setprio(1);
#pragma unroll
    for (int db = 0; db < 4; ++db) {
      bf16x8 vf0 = *(const bf16x8*)&vl[db * 1024 + l31 * 32 + vcol0];
      ct[db] = mfma32(vf0, pf0, ct[db]);
      bf16x8 vf1 = *(const bf16x8*)&vl[db * 1024 + l31 * 32 + vcol1];
      ct[db] = mfma32(vf1, pf1, ct[db]);
    }
    __builtin_amdgcn_s_setprio(0);

    __syncthreads();
  }
#undef STAGE

  const float gsig = 1.f / (1.f + __expf(-gate[0]));
  const float inv = gsig / l_run;
  u16* c_lds = smem + wave * 4352;    // 32 rows x 136 u16
#pragma unroll
  for (int db = 0; db < 4; ++db)
#pragma unroll
    for (int rq = 0; rq < 4; ++rq) {
      us4 o = { f2bf(ct[db][rq * 4 + 0] * inv), f2bf(ct[db][rq * 4 + 1] * inv),
                f2bf(ct[db][rq * 4 + 2] * inv), f2bf(ct[db][rq * 4 + 3] * inv) };
      *(us4*)&c_lds[l31 * 136 + db * 32 + rq * 8 + hi * 4] = o;
    }
  u16* crow = ctx + (size_t)(b * T_ + tw) * HID_ + h * HD_;
#pragma unroll
  for (int rep = 0; rep < 8; ++rep) {
    const int tt = (lane >> 4) + rep * 4;
    us8 valv = *(const us8*)&c_lds[tt * 136 + (lane & 15) * 8];
    *(us8*)&crow[(size_t)tt * HID_ + (lane & 15) * 8] = valv;
  }
}

// ---------------- launch ----------------
extern "C" void kernel_launch(void* const* d_in, const int* in_sizes, int n_in,
                              void* d_out, int out_size, void* d_ws, size_t ws_size,
                              hipStream_t stream) {
  (void)in_sizes; (void)n_in; (void)out_size; (void)ws_size;
  const float* hs   = (const float*)d_in[0];
  const float* nts  = (const float*)d_in[1];
  const int*   mask = (const int*)d_in[2];
  const float* qw   = (const float*)d_in[3];
  const float* qb   = (const float*)d_in[4];
  const float* kw   = (const float*)d_in[5];
  const float* kbi  = (const float*)d_in[6];
  const float* vw   = (const float*)d_in[7];
  const float* vbi  = (const float*)d_in[8];
  const float* ow   = (const float*)d_in[9];
  const float* obi  = (const float*)d_in[10];
  const float* gate = (const float*)d_in[11];
  float* out = (float*)d_out;

  char* w = (char*)d_ws;
  u16* h_bf   = (u16*)(w + 0);          // 33,554,432 B
  u16* n_bf   = (u16*)(w + 33554432);   //  4,194,304 B
  u16* qw_bf  = (u16*)(w + 37748736);   //  8,388,608 B
  u16* kw_bf  = (u16*)(w + 46137344);   //  4,194,304 B
  u16* vw_bf  = (u16*)(w + 50331648);   //  4,194,304 B
  u16* ow_bf  = (u16*)(w + 54525952);   //  8,388,608 B
  u16* q_bf   = (u16*)(w + 62914560);   // 33,554,432 B
  u16* k_bf   = (u16*)(w + 96468992);   //  8,388,608 B
  u16* v_bf   = (u16*)(w + 104857600);  //  8,388,608 B
  u16* vt_bf  = (u16*)(w + 113246208);  //  8,388,608 B  (end 121,634,816)
  u16* ctx_bf = h_bf;                   // alias: hidden_bf16 dead after Q-proj

  hipFuncSetAttribute(reinterpret_cast<const void*>(&gemm_pipe<true>),
                      hipFuncAttributeMaxDynamicSharedMemorySize, 131072);
  hipFuncSetAttribute(reinterpret_cast<const void*>(&gemm_pipe<false>),
                      hipFuncAttributeMaxDynamicSharedMemorySize, 131072);

  convert_all<<<dim3(2048), dim3(256), 0, stream>>>(
      hs, nts, qw, kw, vw, ow, h_bf, n_bf, qw_bf, kw_bf, vw_bf, ow_bf);
  gemm_bt<true><<<dim3(16, 16), dim3(256), 0, stream>>>(
      n_bf, kw_bf, kbi, k_bf, 2048, 2048, 1024);
  gemm_bt<true><<<dim3(16, 16), dim3(256), 0, stream>>>(
      n_bf, vw_bf, vbi, v_bf, 2048, 2048, 1024);
  transpose_v<<<dim3(16, 64, 4), dim3(256), 0, stream>>>(v_bf, vt_bf);
  // Q projection: M=8192, N=2048, K=2048 — grid 8x32 = 256 blocks (1/CU)
  gemm_pipe<true><<<dim3(8, 32), dim3(512), 131072, stream>>>(
      h_bf, qw_bf, qb, q_bf, 8192, 2048, 2048);
  attn_fwd<<<dim3(16, 64), dim3(256), 0, stream>>>(
      q_bf, k_bf, vt_bf, mask, gate, ctx_bf);
  // Output projection -> fp32 d_out
  gemm_pipe<false><<<dim3(8, 32), dim3(512), 131072, stream>>>(
      ctx_bf, ow_bf, obi, out, 8192, 2048, 2048);
}